// Round 11
// baseline (99.419 us; speedup 1.0000x reference)
//
#include <hip/hip_runtime.h>

#define NCHEB 8

typedef __attribute__((ext_vector_type(8))) short vs8;
typedef __attribute__((ext_vector_type(4))) float vf4;
typedef __attribute__((ext_vector_type(16))) float vf16;

__device__ __forceinline__ unsigned short f2bf(float f) {
  union { float f; unsigned int u; } x; x.f = f;
  unsigned int r = (x.u + 0x7FFFu + ((x.u >> 16) & 1u)) >> 16;
  return (unsigned short)r;
}

// Device-scope single-use grid barrier (counters zeroed via hipMemsetAsync).
__device__ __forceinline__ void gbar(unsigned* c, unsigned nblk) {
  __syncthreads();
  if (threadIdx.x == 0) {
    __builtin_amdgcn_fence(__ATOMIC_RELEASE, "agent");
    __hip_atomic_fetch_add(c, 1u, __ATOMIC_RELAXED, __HIP_MEMORY_SCOPE_AGENT);
    while (__hip_atomic_load(c, __ATOMIC_RELAXED, __HIP_MEMORY_SCOPE_AGENT) < nblk)
      __builtin_amdgcn_s_sleep(8);
    __builtin_amdgcn_fence(__ATOMIC_ACQUIRE, "agent");
  }
  __syncthreads();
}

// ---------------------------------------------------------------------------
// Wave-local Chebyshev(NCHEB)-PCG, shuffle SpMV. Executed by ONE wave
// (threads 0..63 of a block). unit in [0,32): sys = unit>>1, comp = unit&1.
// ---------------------------------------------------------------------------
__device__ void pcg_unit(
    int unit, const float* __restrict__ att, const float* __restrict__ grad,
    float* __restrict__ sol, int maxit, float tol2) {
  const int sys = unit >> 1;
  const int wv = unit & 1;
  const int l = threadIdx.x & 63;
  const int row = l >> 2, c4 = l & 3;
  const int i0 = 4 * l;

  const int n = sys >> 2, g = sys & 3;
  const float* ab = att + (n * 40 + g * 10) * 256;
  const float* gb = grad + (n * 40 + g * 10) * 256;

  int era, eda, erb, edb, ec, fa, fb;
  if (wv == 0) { fa = 0; fb = 2; era = 4; eda = 9; erb = 2; edb = 7; ec = 0; }
  else         { fa = 1; fb = 3; era = 8; eda = 5; erb = 6; edb = 3; ec = 1; }

  auto L4 = [](const float* p) { return *reinterpret_cast<const float4*>(p); };
  auto unp = [](float4 v, float* o) { o[0] = v.x; o[1] = v.y; o[2] = v.z; o[3] = v.w; };

  float wLa[4], wRa[4], wUa[4], wDa[4], wXa[4], dga[4], iva[4], rsa[4];
  float wLb[4], wRb[4], wUb[4], wDb[4], wXb[4], dgb[4], ivb[4], rsb[4];

  float rA[4], gA[4], dA[4], hA[4], uA[4] = {0,0,0,0}, vA[4] = {0,0,0,0};
  unp(L4(ab + era * 256 + i0), rA); unp(L4(gb + era * 256 + i0), gA);
  unp(L4(ab + eda * 256 + i0), dA); unp(L4(gb + eda * 256 + i0), hA);
  if (row > 0) { unp(L4(ab + eda * 256 + i0 - 16), uA); unp(L4(gb + eda * 256 + i0 - 16), vA); }
  float rlA = (l > 0) ? ab[era * 256 + i0 - 1] : 0.f;
  float glA = (l > 0) ? gb[era * 256 + i0 - 1] : 0.f;
  float cX[4], gX[4], cU[4] = {0,0,0,0}, gU[4] = {0,0,0,0};
  unp(L4(ab + ec * 256 + i0), cX); unp(L4(gb + ec * 256 + i0), gX);
  float clX = 0.f, glX = 0.f;
  if (wv == 0) { if (l > 0) { clX = ab[ec * 256 + i0 - 1]; glX = gb[ec * 256 + i0 - 1]; } }
  else if (row > 0) { unp(L4(ab + ec * 256 + i0 - 16), cU); unp(L4(gb + ec * 256 + i0 - 16), gU); }

  #pragma unroll
  for (int k = 0; k < 4; ++k) {
    wRa[k] = (k < 3 || c4 < 3) ? rA[k] * rA[k] : 0.f;
    wLa[k] = (k > 0) ? rA[k-1] * rA[k-1] : ((c4 > 0) ? rlA * rlA : 0.f);
    wDa[k] = (row < 15) ? dA[k] * dA[k] : 0.f;
    wUa[k] = (row > 0) ? uA[k] * uA[k] : 0.f;
    float rhs = wRa[k] * gA[k] - wLa[k] * ((k > 0) ? gA[k-1] : glA)
              + wDa[k] * hA[k] - wUa[k] * vA[k];
    float wx, gx;
    if (wv == 0) {
      wx = (k > 0) ? cX[k-1] * cX[k-1] : ((c4 > 0) ? clX * clX : 0.f);
      gx = (k > 0) ? gX[k-1] : glX;
    } else {
      wx = (row > 0) ? cU[k] * cU[k] : 0.f;
      gx = gU[k];
    }
    wXa[k] = wx;
    rhs -= wx * gx;
    rsa[k] = rhs;
    dga[k] = 1e-12f + wRa[k] + wLa[k] + wDa[k] + wUa[k] + wx;
  }

  float rB[4], gB[4], dB[4], hB[4], uB[4] = {0,0,0,0}, vB[4] = {0,0,0,0};
  unp(L4(ab + erb * 256 + i0), rB); unp(L4(gb + erb * 256 + i0), gB);
  unp(L4(ab + edb * 256 + i0), dB); unp(L4(gb + edb * 256 + i0), hB);
  if (row > 0) { unp(L4(ab + edb * 256 + i0 - 16), uB); unp(L4(gb + edb * 256 + i0 - 16), vB); }
  float rlB = (l > 0) ? ab[erb * 256 + i0 - 1] : 0.f;
  float glB = (l > 0) ? gb[erb * 256 + i0 - 1] : 0.f;

  #pragma unroll
  for (int k = 0; k < 4; ++k) {
    wRb[k] = (k < 3 || c4 < 3) ? rB[k] * rB[k] : 0.f;
    wLb[k] = (k > 0) ? rB[k-1] * rB[k-1] : ((c4 > 0) ? rlB * rlB : 0.f);
    wDb[k] = (row < 15) ? dB[k] * dB[k] : 0.f;
    wUb[k] = (row > 0) ? uB[k] * uB[k] : 0.f;
    float wx;
    if (wv == 0) wx = (k < 3 || c4 < 3) ? cX[k] * cX[k] : 0.f;
    else         wx = (row < 15) ? cX[k] * cX[k] : 0.f;
    wXb[k] = wx;
    rsb[k] = wRb[k] * gB[k] - wLb[k] * ((k > 0) ? gB[k-1] : glB)
           + wDb[k] * hB[k] - wUb[k] * vB[k]
           + wx * gX[k];
    dgb[k] = 1e-12f + wRb[k] + wLb[k] + wDb[k] + wUb[k] + wx;
  }

  if (l == 63) {
    float wr = rA[3] * rA[3], wd = dA[3] * dA[3];
    dga[3] += wr + wd;
    rsa[3] += wr * gA[3] + wd * hA[3];
    float wc = cX[3] * cX[3], wrb = rB[3] * rB[3], wdb = dB[3] * dB[3];
    dgb[3] += wc + wrb + wdb;
    rsb[3] += wc * gX[3] + wrb * gB[3] + wdb * hB[3];
  }
  #pragma unroll
  for (int k = 0; k < 4; ++k) { iva[k] = 1.f / dga[k]; ivb[k] = 1.f / dgb[k]; }

  float ua[4], ub[4], wa[4], wb[4];

  auto spmv = [&](const float (&ia_)[4], const float (&ib_)[4],
                  float (&oa)[4], float (&ob)[4]) {
    float aU[4], aD[4], bU[4], bD[4];
    #pragma unroll
    for (int k = 0; k < 4; ++k) {
      aU[k] = __shfl_up(ia_[k], 4, 64);
      aD[k] = __shfl_down(ia_[k], 4, 64);
      bU[k] = __shfl_up(ib_[k], 4, 64);
      bD[k] = __shfl_down(ib_[k], 4, 64);
    }
    float aL = __shfl_up(ia_[3], 1, 64);
    float aR = __shfl_down(ia_[0], 1, 64);
    float bL = __shfl_up(ib_[3], 1, 64);
    float bR = __shfl_down(ib_[0], 1, 64);
    float uaL[4] = {aL, ia_[0], ia_[1], ia_[2]};
    float uaR[4] = {ia_[1], ia_[2], ia_[3], aR};
    float ubL[4] = {bL, ib_[0], ib_[1], ib_[2]};
    float ubR[4] = {ib_[1], ib_[2], ib_[3], bR};
    #pragma unroll
    for (int k = 0; k < 4; ++k) {
      float cA = (wv == 0) ? ubL[k] : bU[k];
      float cB = (wv == 0) ? uaR[k] : aD[k];
      oa[k] = dga[k] * ia_[k] - wLa[k] * uaL[k] - wRa[k] * uaR[k]
            - wUa[k] * aU[k] - wDa[k] * aD[k] - wXa[k] * cA;
      ob[k] = dgb[k] * ib_[k] - wLb[k] * ubL[k] - wRb[k] * ubR[k]
            - wUb[k] * bU[k] - wDb[k] * bD[k] - wXb[k] * cB;
    }
  };

  constexpr float lo = 0.01f, hi = 2.0f;
  constexpr float th = (hi + lo) * 0.5f, dl = (hi - lo) * 0.5f, s1 = th / dl;

  float xa[4] = {0,0,0,0}, xb[4] = {0,0,0,0};
  float ra_[4], rb_[4], pa[4] = {0,0,0,0}, pb_[4] = {0,0,0,0};
  float sa[4] = {0,0,0,0}, sb[4] = {0,0,0,0};
  #pragma unroll
  for (int k = 0; k < 4; ++k) { ra_[k] = rsa[k]; rb_[k] = rsb[k]; }

  auto cheb = [&]() {
    float da_[4], db_[4], ta[4], tb[4], qa[4], qb[4];
    #pragma unroll
    for (int k = 0; k < 4; ++k) {
      da_[k] = (1.0f / th) * iva[k] * ra_[k];
      db_[k] = (1.0f / th) * ivb[k] * rb_[k];
      ua[k] = da_[k]; ub[k] = db_[k];
    }
    spmv(da_, db_, ta, tb);
    #pragma unroll
    for (int k = 0; k < 4; ++k) {
      wa[k] = ta[k]; wb[k] = tb[k];
      qa[k] = ra_[k] - ta[k]; qb[k] = rb_[k] - tb[k];
    }
    float rho = 1.0f / s1;
    #pragma unroll
    for (int j = 1; j < NCHEB; ++j) {
      float rho2 = 1.0f / (2.0f * s1 - rho);
      float c1 = rho2 * rho, c2 = 2.0f * rho2 / dl;
      #pragma unroll
      for (int k = 0; k < 4; ++k) {
        da_[k] = c1 * da_[k] + c2 * iva[k] * qa[k];
        db_[k] = c1 * db_[k] + c2 * ivb[k] * qb[k];
        ua[k] += da_[k]; ub[k] += db_[k];
      }
      spmv(da_, db_, ta, tb);
      #pragma unroll
      for (int k = 0; k < 4; ++k) {
        wa[k] += ta[k]; wb[k] += tb[k];
        qa[k] -= ta[k]; qb[k] -= tb[k];
      }
      rho = rho2;
    }
  };

  float gamma, delta;
  auto dots = [&]() {
    float gp = 0.f, dp = 0.f;
    #pragma unroll
    for (int k = 0; k < 4; ++k) {
      gp += ra_[k] * ua[k] + rb_[k] * ub[k];
      dp += wa[k] * ua[k] + wb[k] * ub[k];
    }
    #pragma unroll
    for (int o = 1; o <= 32; o <<= 1) {
      gp += __shfl_xor(gp, o, 64);
      dp += __shfl_xor(dp, o, 64);
    }
    gamma = gp; delta = dp;
  };

  cheb();
  dots();
  const float thresh = tol2 * gamma;
  float gamma_old = gamma, alpha_old = 1.f;

  for (int it = 0; it < maxit && gamma > thresh; ++it) {
    float beta = (it == 0) ? 0.f : gamma / gamma_old;
    float alpha = (it == 0) ? gamma / delta
                            : gamma / (delta - beta * gamma / alpha_old);
    #pragma unroll
    for (int k = 0; k < 4; ++k) {
      pa[k] = ua[k] + beta * pa[k];   pb_[k] = ub[k] + beta * pb_[k];
      sa[k] = wa[k] + beta * sa[k];   sb[k] = wb[k] + beta * sb[k];
      xa[k] += alpha * pa[k];         xb[k] += alpha * pb_[k];
      ra_[k] -= alpha * sa[k];        rb_[k] -= alpha * sb[k];
    }
    gamma_old = gamma; alpha_old = alpha;
    cheb();
    dots();
  }

  float4* sol4 = reinterpret_cast<float4*>(sol);
  sol4[sys * 256 + fa * 64 + l] = make_float4(xa[0], xa[1], xa[2], xa[3]);
  sol4[sys * 256 + fb * 64 + l] = make_float4(xb[0], xb[1], xb[2], xb[3]);
}

// ---------------------------------------------------------------------------
// Single fused kernel: 32 blocks x 512 threads (1 block/CU).
//   blocks 0-7 : conv1 -> LDS -> conv2 (+SE on even blocks)   [phase 1]
//   all blocks : pcg unit on wave 0 only (1 wave/CU)           [phase 2]
//   blocks 0-3 : GroupNorm + SE + post conv                    [phase 3]
// ---------------------------------------------------------------------------
__global__ __launch_bounds__(512, 1) void k_all(
    const float* __restrict__ x,
    const float* __restrict__ w1g, const float* __restrict__ b1g,
    const float* __restrict__ w1a, const float* __restrict__ b1a,
    const float* __restrict__ w2g, const float* __restrict__ b2g,
    const float* __restrict__ w2a, const float* __restrict__ b2a,
    const float* __restrict__ sw1, const float* __restrict__ sb1,
    const float* __restrict__ sw2, const float* __restrict__ sb2,
    const float* __restrict__ gn_w, const float* __restrict__ gn_b,
    const float* __restrict__ pw, const float* __restrict__ pb,
    float* __restrict__ grad, float* __restrict__ att,
    float* __restrict__ seb, float* __restrict__ solb,
    float* __restrict__ out, unsigned* __restrict__ bar) {
  __shared__ __attribute__((aligned(16))) unsigned char smem[84352];
  // front mapping
  unsigned short* Xl = (unsigned short*)smem;              // 32768 B
  unsigned short* Yl = (unsigned short*)(smem + 32768);    // 32768 B
  unsigned short* Wt = (unsigned short*)(smem + 65536);    // 18432 B
  float* sp  = (float*)(smem + 83968);                     // 256 B
  float* sh1 = (float*)(smem + 84224);                     // 128 B
  // post mapping (aliases front storage; phases separated by grid barrier)
  unsigned short* Hl = (unsigned short*)smem;              // 12288 B
  unsigned short* Wp = (unsigned short*)(smem + 12288);    // 55296 B
  float* rs  = (float*)(smem + 67584);                     // 32 B
  float* rs2 = (float*)(smem + 67616);                     // 32 B

  const int bid = blockIdx.x;
  const int t = threadIdx.x;

  // ======================= phase 1: front =======================
  if (bid < 8) {
    const int br = bid & 1;
    const int n = bid >> 1;
    const float* inp = x + n * 64 * 256;

    // stage X: [pix][ci] bf16, chunk c' = chunk ^ (pix&7)
    {
      const int p = t & 255, hf = t >> 8;
      #pragma unroll
      for (int qq = 0; qq < 4; ++qq) {
        const int q8 = hf * 4 + qq;
        vs8 v;
        #pragma unroll
        for (int j = 0; j < 8; ++j) v[j] = (short)f2bf(inp[(8 * q8 + j) * 256 + p]);
        *(vs8*)&Xl[p * 64 + ((q8 ^ (p & 7)) << 3)] = v;
      }
    }

    // SE (even blocks; block-local syncs)
    if (br == 0) {
      if (t < 256) {
        const int c = t >> 2, part = t & 3;
        const float* xp = inp + c * 256 + part * 64;
        float s = 0.f;
        for (int k = 0; k < 64; ++k) s += xp[k];
        s += __shfl_xor(s, 1, 64);
        s += __shfl_xor(s, 2, 64);
        if (part == 0) sp[c] = s * (1.f / 256.f);
      }
      __syncthreads();
      if (t < 32) {
        float a = sb1[t];
        for (int k = 0; k < 64; ++k) a += sw1[t * 64 + k] * sp[k];
        sh1[t] = a > 0.f ? a : 0.01f * a;
      }
      __syncthreads();
      if (t < 16) {
        float a = sb2[t];
        for (int k = 0; k < 32; ++k) a += sw2[t * 32 + k] * sh1[k];
        seb[n * 16 + t] = 1.f / (1.f + __expf(-a));
      }
    }

    const float* w1 = br ? w1a : w1g;
    const float* b1 = br ? b1a : b1g;
    const int w = t >> 6, lane = t & 63;
    const int px = lane & 15, kg = lane >> 4;

    // conv1: 4 co-tile rounds; wave w owns image rows {2w, 2w+1}
    for (int ct = 0; ct < 4; ++ct) {
      __syncthreads();
      {
        const int col = t >> 5, sub = t & 31;
        const float* wp1 = w1 + ((ct * 16 + col) * 64 + sub * 2) * 9;
        #pragma unroll
        for (int cc = 0; cc < 2; ++cc) {
          const int ci = sub * 2 + cc;
          #pragma unroll
          for (int e = 0; e < 9; ++e)
            Wt[(e * 16 + col) * 64 + (ci ^ ((col & 7) << 3))] = f2bf(wp1[cc * 9 + e]);
        }
      }
      __syncthreads();
      vf4 acc[2];
      acc[0] = (vf4)0.f; acc[1] = (vf4)0.f;
      for (int e = 0; e < 9; ++e) {
        const int dy = e / 3 - 1, dx = e % 3 - 1;
        const bool xok = (dx == 0) || (dx < 0 ? (px > 0) : (px < 15));
        const int xoff = xok ? dx : 0;
        #pragma unroll
        for (int ks = 0; ks < 2; ++ks) {
          vs8 bf = *(const vs8*)&Wt[(e * 16 + px) * 64 + (((ks * 4 + kg) ^ (px & 7)) << 3)];
          #pragma unroll
          for (int mm = 0; mm < 2; ++mm) {
            const int yy = 2 * w + mm + dy;
            if (yy < 0 || yy > 15) continue;
            const int ps = yy * 16 + px + xoff;
            vs8 a = *(const vs8*)&Xl[ps * 64 + (((ks * 4 + kg) ^ (ps & 7)) << 3)];
            if (!xok) a = (vs8)(short)0;
            acc[mm] = __builtin_amdgcn_mfma_f32_16x16x32_bf16(a, bf, acc[mm], 0, 0, 0);
          }
        }
      }
      const int co = ct * 16 + px;
      const float bv = b1[co];
      #pragma unroll
      for (int mm = 0; mm < 2; ++mm) {
        const int y = 2 * w + mm;
        #pragma unroll
        for (int j = 0; j < 4; ++j) {
          float s = acc[mm][j] + bv;
          s = s > 0.f ? s : 0.01f * s;
          const int p = y * 16 + kg * 4 + j;
          Yl[p * 64 + (((co >> 3) ^ (p & 7)) << 3) + (co & 7)] = f2bf(s);
        }
      }
    }

    // conv2: 3 co-tile rounds from Yl -> global grad/att
    const float* w2 = br ? w2a : w2g;
    const float* b2 = br ? b2a : b2g;
    float* outp = (br ? att : grad) + n * 40 * 256;
    for (int ct = 0; ct < 3; ++ct) {
      __syncthreads();
      {
        const int col = t >> 5, sub = t & 31;
        const int co = ct * 16 + col;
        if (co < 40) {
          const float* wp2 = w2 + (co * 64 + sub * 2) * 9;
          #pragma unroll
          for (int cc = 0; cc < 2; ++cc) {
            const int ci = sub * 2 + cc;
            #pragma unroll
            for (int e = 0; e < 9; ++e)
              Wt[(e * 16 + col) * 64 + (ci ^ ((col & 7) << 3))] = f2bf(wp2[cc * 9 + e]);
          }
        } else {
          #pragma unroll
          for (int cc = 0; cc < 2; ++cc) {
            const int ci = sub * 2 + cc;
            #pragma unroll
            for (int e = 0; e < 9; ++e)
              Wt[(e * 16 + col) * 64 + (ci ^ ((col & 7) << 3))] = 0;
          }
        }
      }
      __syncthreads();
      vf4 acc[2];
      acc[0] = (vf4)0.f; acc[1] = (vf4)0.f;
      for (int e = 0; e < 9; ++e) {
        const int dy = e / 3 - 1, dx = e % 3 - 1;
        const bool xok = (dx == 0) || (dx < 0 ? (px > 0) : (px < 15));
        const int xoff = xok ? dx : 0;
        #pragma unroll
        for (int ks = 0; ks < 2; ++ks) {
          vs8 bf = *(const vs8*)&Wt[(e * 16 + px) * 64 + (((ks * 4 + kg) ^ (px & 7)) << 3)];
          #pragma unroll
          for (int mm = 0; mm < 2; ++mm) {
            const int yy = 2 * w + mm + dy;
            if (yy < 0 || yy > 15) continue;
            const int ps = yy * 16 + px + xoff;
            vs8 a = *(const vs8*)&Yl[ps * 64 + (((ks * 4 + kg) ^ (ps & 7)) << 3)];
            if (!xok) a = (vs8)(short)0;
            acc[mm] = __builtin_amdgcn_mfma_f32_16x16x32_bf16(a, bf, acc[mm], 0, 0, 0);
          }
        }
      }
      const int co = ct * 16 + px;
      if (co < 40) {
        const float bv = b2[co];
        #pragma unroll
        for (int mm = 0; mm < 2; ++mm) {
          const int y = 2 * w + mm;
          vf4 v = acc[mm];
          #pragma unroll
          for (int j = 0; j < 4; ++j) {
            float s = v[j] + bv;
            if (br) s = 1.f / (1.f + __expf(-s));
            v[j] = s;
          }
          *(vf4*)&outp[co * 256 + y * 16 + kg * 4] = v;
        }
      }
    }
  }
  gbar(bar, 32);

  // ======================= phase 2: pcg (wave 0 of every block) ============
  if (t < 64) pcg_unit(bid, att, grad, solb, 100, 3e-6f);
  gbar(bar + 64, 32);

  // ======================= phase 3: post (blocks 0-3) ======================
  if (bid < 4) {
    const int n = bid;
    const int w = t >> 6, lane = t & 63;

    float v[8];
    {
      const vf4* s4 = (const vf4*)(solb + n * 4096 + 8 * t);
      vf4 a = s4[0], b = s4[1];
      v[0]=a[0];v[1]=a[1];v[2]=a[2];v[3]=a[3];v[4]=b[0];v[5]=b[1];v[6]=b[2];v[7]=b[3];
    }
    float s = 0.f, s2 = 0.f;
    #pragma unroll
    for (int k = 0; k < 8; ++k) { s += v[k]; s2 += v[k] * v[k]; }
    #pragma unroll
    for (int o = 1; o <= 32; o <<= 1) { s += __shfl_xor(s, o, 64); s2 += __shfl_xor(s2, o, 64); }
    if (lane == 0) { rs[w] = s; rs2[w] = s2; }

    // stage W (division-free)
    {
      const int co = t >> 2, sub = t & 3;
      const float* wp0 = pw + (co * 16 + sub * 4) * 9;
      #pragma unroll
      for (int cc = 0; cc < 4; ++cc) {
        const int ci = sub * 4 + cc;
        #pragma unroll
        for (int e = 0; e < 9; ++e)
          Wp[(e * 128 + co) * 24 + ci] = f2bf(wp0[cc * 9 + e]);
      }
    }
    __syncthreads();
    float sm = 0.f, sq = 0.f;
    #pragma unroll
    for (int k = 0; k < 8; ++k) { sm += rs[k]; sq += rs2[k]; }
    const float mu = sm * (1.f / 4096.f);
    const float rstd = rsqrtf(sq * (1.f / 4096.f) - mu * mu + 1e-5f);

    const int c = t >> 5;
    const int p0 = (8 * t) & 255;
    const float sev = seb[n * 16 + c];
    const float sc = rstd * gn_w[c] * sev;
    const float of = (gn_b[c] - mu * rstd * gn_w[c]) * sev;
    #pragma unroll
    for (int k = 0; k < 8; ++k) Hl[(p0 + k) * 24 + c] = f2bf(v[k] * sc + of);
    __syncthreads();

    const int cl = lane & 31, h = lane >> 5;
    const int px = cl & 15, y0 = 2 * w + (cl >> 4);
    vf16 acc[4];
    #pragma unroll
    for (int nt = 0; nt < 4; ++nt) acc[nt] = (vf16)0.f;
    for (int e = 0; e < 9; ++e) {
      const int dy = e / 3 - 1, dx = e % 3 - 1;
      const int yy = y0 + dy, xx = px + dx;
      const bool ok = (yy >= 0 && yy < 16 && xx >= 0 && xx < 16);
      const int ps = ok ? yy * 16 + xx : 0;
      vs8 a = *(const vs8*)&Hl[ps * 24 + h * 8];
      if (!ok) a = (vs8)(short)0;
      #pragma unroll
      for (int nt = 0; nt < 4; ++nt) {
        vs8 bf = *(const vs8*)&Wp[(e * 128 + nt * 32 + cl) * 24 + h * 8];
        acc[nt] = __builtin_amdgcn_mfma_f32_32x32x16_bf16(a, bf, acc[nt], 0, 0, 0);
      }
    }
    float* op = out + n * 32768;
    #pragma unroll
    for (int nt = 0; nt < 4; ++nt) {
      const int co = nt * 32 + cl;
      const float bv = pb[co];
      #pragma unroll
      for (int rq = 0; rq < 4; ++rq) {
        vf4 vv;
        #pragma unroll
        for (int j = 0; j < 4; ++j) vv[j] = acc[nt][rq * 4 + j] + bv;
        *(vf4*)&op[co * 256 + 32 * w + 8 * rq + 4 * h] = vv;
      }
    }
  }
}

extern "C" void kernel_launch(void* const* d_in, const int* in_sizes, int n_in,
                              void* d_out, int out_size, void* d_ws, size_t ws_size,
                              hipStream_t stream) {
  const float* x       = (const float*)d_in[0];
  const float* grad_w1 = (const float*)d_in[1];
  const float* grad_b1 = (const float*)d_in[2];
  const float* grad_w2 = (const float*)d_in[3];
  const float* grad_b2 = (const float*)d_in[4];
  const float* att_w1  = (const float*)d_in[5];
  const float* att_b1  = (const float*)d_in[6];
  const float* att_w2  = (const float*)d_in[7];
  const float* att_b2  = (const float*)d_in[8];
  const float* se_w1   = (const float*)d_in[9];
  const float* se_b1   = (const float*)d_in[10];
  const float* se_w2   = (const float*)d_in[11];
  const float* se_b2   = (const float*)d_in[12];
  const float* gn_w    = (const float*)d_in[13];
  const float* gn_b    = (const float*)d_in[14];
  const float* post_w  = (const float*)d_in[15];
  const float* post_b  = (const float*)d_in[16];
  float* out = (float*)d_out;
  float* ws = (float*)d_ws;

  float* gradb = ws;            // 40960 floats
  float* attb  = ws + 40960;    // 40960
  float* seb   = ws + 81920;    // 64
  float* solb  = ws + 81984;    // 16384
  unsigned* bar = (unsigned*)(ws + 98368); // 2 counters, 256B apart

  hipMemsetAsync(bar, 0, 512, stream);
  k_all<<<32, 512, 0, stream>>>(
      x, grad_w1, grad_b1, att_w1, att_b1,
      grad_w2, grad_b2, att_w2, att_b2,
      se_w1, se_b1, se_w2, se_b2,
      gn_w, gn_b, post_w, post_b,
      gradb, attb, seb, solb, out, bar);
}

// Round 12
// 82.927 us; speedup vs baseline: 1.1989x; 1.1989x over previous
//
#include <hip/hip_runtime.h>

#define NCHEB 8

typedef __attribute__((ext_vector_type(8))) short vs8;
typedef __attribute__((ext_vector_type(4))) float vf4;
typedef __attribute__((ext_vector_type(16))) float vf16;

__device__ __forceinline__ unsigned short f2bf(float f) {
  union { float f; unsigned int u; } x; x.f = f;
  unsigned int r = (x.u + 0x7FFFu + ((x.u >> 16) & 1u)) >> 16;
  return (unsigned short)r;
}

// DPP move: ctrl 0x138 = wave_shr:1 (lane l <- l-1), 0x130 = wave_shl:1
// (lane l <- l+1), 0xB1 = quad_perm[1,0,3,2] (xor1), 0x4E = quad_perm[2,3,0,1]
// (xor2), 0x128 = row_ror:8 (xor8 within 16-lane rows).
template<int CTRL>
__device__ __forceinline__ float dppf(float x) {
  return __int_as_float(__builtin_amdgcn_mov_dpp(__float_as_int(x), CTRL, 0xF, 0xF, true));
}

// Point-to-point release/acquire flags (private 64B lines, zeroed by
// hipMemsetAsync each launch). Relaxed agent-scope polls reach the coherence
// point (same mechanism as R11's counters); acquire fence after success.
__device__ __forceinline__ void flag_set(unsigned* f) {
  __builtin_amdgcn_fence(__ATOMIC_RELEASE, "agent");
  __hip_atomic_store(f, 1u, __ATOMIC_RELAXED, __HIP_MEMORY_SCOPE_AGENT);
}
__device__ __forceinline__ void flag_wait(unsigned* f) {
  while (__hip_atomic_load(f, __ATOMIC_RELAXED, __HIP_MEMORY_SCOPE_AGENT) == 0u)
    __builtin_amdgcn_s_sleep(2);
}

// ---------------------------------------------------------------------------
// Wave-local Chebyshev(NCHEB)-PCG, DPP SpMV. One wave per unit.
// NEW layout: lane l owns pixels (y = l&15, x = 4*(l>>4)+k), k=0..3, both
// fields. up/down (y+-1) = lane +-1 -> DPP wave_shr/shl (VALU pipe);
// left/right column-edge = lane +-16 (4 shuffles/spmv). Weight setup is
// address-identical to the old layout with row=l&15, c4=l>>4, i0=16*row+4*c4.
// ---------------------------------------------------------------------------
__device__ void pcg_unit(
    int unit, const float* __restrict__ att, const float* __restrict__ grad,
    float* __restrict__ sol, int maxit, float tol2) {
  const int sys = unit >> 1;
  const int wv = unit & 1;
  const int l = threadIdx.x & 63;
  const int row = l & 15;        // y
  const int c4 = l >> 4;         // column group (x = 4*c4 + k)
  const int i0 = 16 * row + 4 * c4;

  const int n = sys >> 2, g = sys & 3;
  const float* ab = att + (n * 40 + g * 10) * 256;
  const float* gb = grad + (n * 40 + g * 10) * 256;

  int era, eda, erb, edb, ec, fa, fb;
  if (wv == 0) { fa = 0; fb = 2; era = 4; eda = 9; erb = 2; edb = 7; ec = 0; }
  else         { fa = 1; fb = 3; era = 8; eda = 5; erb = 6; edb = 3; ec = 1; }

  auto L4 = [](const float* p) { return *reinterpret_cast<const float4*>(p); };
  auto unp = [](float4 v, float* o) { o[0] = v.x; o[1] = v.y; o[2] = v.z; o[3] = v.w; };

  float wLa[4], wRa[4], wUa[4], wDa[4], wXa[4], dga[4], iva[4], rsa[4];
  float wLb[4], wRb[4], wUb[4], wDb[4], wXb[4], dgb[4], ivb[4], rsb[4];

  float rA[4], gA[4], dA[4], hA[4], uA[4] = {0,0,0,0}, vA[4] = {0,0,0,0};
  unp(L4(ab + era * 256 + i0), rA); unp(L4(gb + era * 256 + i0), gA);
  unp(L4(ab + eda * 256 + i0), dA); unp(L4(gb + eda * 256 + i0), hA);
  if (row > 0) { unp(L4(ab + eda * 256 + i0 - 16), uA); unp(L4(gb + eda * 256 + i0 - 16), vA); }
  float rlA = (l > 0) ? ab[era * 256 + i0 - 1] : 0.f;
  float glA = (l > 0) ? gb[era * 256 + i0 - 1] : 0.f;
  float cX[4], gX[4], cU[4] = {0,0,0,0}, gU[4] = {0,0,0,0};
  unp(L4(ab + ec * 256 + i0), cX); unp(L4(gb + ec * 256 + i0), gX);
  float clX = 0.f, glX = 0.f;
  if (wv == 0) { if (l > 0) { clX = ab[ec * 256 + i0 - 1]; glX = gb[ec * 256 + i0 - 1]; } }
  else if (row > 0) { unp(L4(ab + ec * 256 + i0 - 16), cU); unp(L4(gb + ec * 256 + i0 - 16), gU); }

  #pragma unroll
  for (int k = 0; k < 4; ++k) {
    wRa[k] = (k < 3 || c4 < 3) ? rA[k] * rA[k] : 0.f;
    wLa[k] = (k > 0) ? rA[k-1] * rA[k-1] : ((c4 > 0) ? rlA * rlA : 0.f);
    wDa[k] = (row < 15) ? dA[k] * dA[k] : 0.f;
    wUa[k] = (row > 0) ? uA[k] * uA[k] : 0.f;
    float rhs = wRa[k] * gA[k] - wLa[k] * ((k > 0) ? gA[k-1] : glA)
              + wDa[k] * hA[k] - wUa[k] * vA[k];
    float wx, gx;
    if (wv == 0) {
      wx = (k > 0) ? cX[k-1] * cX[k-1] : ((c4 > 0) ? clX * clX : 0.f);
      gx = (k > 0) ? gX[k-1] : glX;
    } else {
      wx = (row > 0) ? cU[k] * cU[k] : 0.f;
      gx = gU[k];
    }
    wXa[k] = wx;
    rhs -= wx * gx;
    rsa[k] = rhs;
    dga[k] = 1e-12f + wRa[k] + wLa[k] + wDa[k] + wUa[k] + wx;
  }

  float rB[4], gB[4], dB[4], hB[4], uB[4] = {0,0,0,0}, vB[4] = {0,0,0,0};
  unp(L4(ab + erb * 256 + i0), rB); unp(L4(gb + erb * 256 + i0), gB);
  unp(L4(ab + edb * 256 + i0), dB); unp(L4(gb + edb * 256 + i0), hB);
  if (row > 0) { unp(L4(ab + edb * 256 + i0 - 16), uB); unp(L4(gb + edb * 256 + i0 - 16), vB); }
  float rlB = (l > 0) ? ab[erb * 256 + i0 - 1] : 0.f;
  float glB = (l > 0) ? gb[erb * 256 + i0 - 1] : 0.f;

  #pragma unroll
  for (int k = 0; k < 4; ++k) {
    wRb[k] = (k < 3 || c4 < 3) ? rB[k] * rB[k] : 0.f;
    wLb[k] = (k > 0) ? rB[k-1] * rB[k-1] : ((c4 > 0) ? rlB * rlB : 0.f);
    wDb[k] = (row < 15) ? dB[k] * dB[k] : 0.f;
    wUb[k] = (row > 0) ? uB[k] * uB[k] : 0.f;
    float wx;
    if (wv == 0) wx = (k < 3 || c4 < 3) ? cX[k] * cX[k] : 0.f;
    else         wx = (row < 15) ? cX[k] * cX[k] : 0.f;
    wXb[k] = wx;
    rsb[k] = wRb[k] * gB[k] - wLb[k] * ((k > 0) ? gB[k-1] : glB)
           + wDb[k] * hB[k] - wUb[k] * vB[k]
           + wx * gX[k];
    dgb[k] = 1e-12f + wRb[k] + wLb[k] + wDb[k] + wUb[k] + wx;
  }

  if (l == 63) {  // pixel 255 = (y15, x15)
    float wr = rA[3] * rA[3], wd = dA[3] * dA[3];
    dga[3] += wr + wd;
    rsa[3] += wr * gA[3] + wd * hA[3];
    float wc = cX[3] * cX[3], wrb = rB[3] * rB[3], wdb = dB[3] * dB[3];
    dgb[3] += wc + wrb + wdb;
    rsb[3] += wc * gX[3] + wrb * gB[3] + wdb * hB[3];
  }
  #pragma unroll
  for (int k = 0; k < 4; ++k) { iva[k] = 1.f / dga[k]; ivb[k] = 1.f / dgb[k]; }

  float ua[4], ub[4], wa[4], wb[4];

  // SpMV: 4 edge shuffles (lane +-16) + 16 DPP wave shifts (VALU pipe).
  auto spmv = [&](const float (&ia_)[4], const float (&ib_)[4],
                  float (&oa)[4], float (&ob)[4]) {
    float aL = __shfl_up(ia_[3], 16, 64);
    float aR = __shfl_down(ia_[0], 16, 64);
    float bL = __shfl_up(ib_[3], 16, 64);
    float bR = __shfl_down(ib_[0], 16, 64);
    float aU[4], aD[4], bU[4], bD[4];
    #pragma unroll
    for (int k = 0; k < 4; ++k) {
      aU[k] = dppf<0x138>(ia_[k]);   // y-1 (lane l-1); lane0 bound -> weight 0
      aD[k] = dppf<0x130>(ia_[k]);   // y+1 (lane l+1); lane63 bound -> weight 0
      bU[k] = dppf<0x138>(ib_[k]);
      bD[k] = dppf<0x130>(ib_[k]);
    }
    float uaL[4] = {aL, ia_[0], ia_[1], ia_[2]};
    float uaR[4] = {ia_[1], ia_[2], ia_[3], aR};
    float ubL[4] = {bL, ib_[0], ib_[1], ib_[2]};
    float ubR[4] = {ib_[1], ib_[2], ib_[3], bR};
    #pragma unroll
    for (int k = 0; k < 4; ++k) {
      float cA = (wv == 0) ? ubL[k] : bU[k];
      float cB = (wv == 0) ? uaR[k] : aD[k];
      oa[k] = dga[k] * ia_[k] - wLa[k] * uaL[k] - wRa[k] * uaR[k]
            - wUa[k] * aU[k] - wDa[k] * aD[k] - wXa[k] * cA;
      ob[k] = dgb[k] * ib_[k] - wLb[k] * ubL[k] - wRb[k] * ubR[k]
            - wUb[k] * bU[k] - wDb[k] * bD[k] - wXb[k] * cB;
    }
  };

  constexpr float lo = 0.01f, hi = 2.0f;
  constexpr float th = (hi + lo) * 0.5f, dl = (hi - lo) * 0.5f, s1 = th / dl;

  float xa[4] = {0,0,0,0}, xb[4] = {0,0,0,0};
  float ra_[4], rb_[4], pa[4] = {0,0,0,0}, pb_[4] = {0,0,0,0};
  float sa[4] = {0,0,0,0}, sb[4] = {0,0,0,0};
  #pragma unroll
  for (int k = 0; k < 4; ++k) { ra_[k] = rsa[k]; rb_[k] = rsb[k]; }

  auto cheb = [&]() {
    float da_[4], db_[4], ta[4], tb[4], qa[4], qb[4];
    #pragma unroll
    for (int k = 0; k < 4; ++k) {
      da_[k] = (1.0f / th) * iva[k] * ra_[k];
      db_[k] = (1.0f / th) * ivb[k] * rb_[k];
      ua[k] = da_[k]; ub[k] = db_[k];
    }
    spmv(da_, db_, ta, tb);
    #pragma unroll
    for (int k = 0; k < 4; ++k) {
      wa[k] = ta[k]; wb[k] = tb[k];
      qa[k] = ra_[k] - ta[k]; qb[k] = rb_[k] - tb[k];
    }
    float rho = 1.0f / s1;
    #pragma unroll
    for (int j = 1; j < NCHEB; ++j) {
      float rho2 = 1.0f / (2.0f * s1 - rho);
      float c1 = rho2 * rho, c2 = 2.0f * rho2 / dl;
      #pragma unroll
      for (int k = 0; k < 4; ++k) {
        da_[k] = c1 * da_[k] + c2 * iva[k] * qa[k];
        db_[k] = c1 * db_[k] + c2 * ivb[k] * qb[k];
        ua[k] += da_[k]; ub[k] += db_[k];
      }
      spmv(da_, db_, ta, tb);
      #pragma unroll
      for (int k = 0; k < 4; ++k) {
        wa[k] += ta[k]; wb[k] += tb[k];
        qa[k] -= ta[k]; qb[k] -= tb[k];
      }
      rho = rho2;
    }
  };

  float gamma, delta;
  auto dots = [&]() {
    float gp = 0.f, dp = 0.f;
    #pragma unroll
    for (int k = 0; k < 4; ++k) {
      gp += ra_[k] * ua[k] + rb_[k] * ub[k];
      dp += wa[k] * ua[k] + wb[k] * ub[k];
    }
    gp += dppf<0xB1>(gp);            dp += dppf<0xB1>(dp);             // xor1
    gp += dppf<0x4E>(gp);            dp += dppf<0x4E>(dp);             // xor2
    gp += __shfl_xor(gp, 4, 64);     dp += __shfl_xor(dp, 4, 64);
    gp += dppf<0x128>(gp);           dp += dppf<0x128>(dp);            // xor8
    gp += __shfl_xor(gp, 16, 64);    dp += __shfl_xor(dp, 16, 64);
    gp += __shfl_xor(gp, 32, 64);    dp += __shfl_xor(dp, 32, 64);
    gamma = gp; delta = dp;
  };

  cheb();
  dots();
  const float thresh = tol2 * gamma;
  float gamma_old = gamma, alpha_old = 1.f;

  for (int it = 0; it < maxit && gamma > thresh; ++it) {
    float beta = (it == 0) ? 0.f : gamma / gamma_old;
    float alpha = (it == 0) ? gamma / delta
                            : gamma / (delta - beta * gamma / alpha_old);
    #pragma unroll
    for (int k = 0; k < 4; ++k) {
      pa[k] = ua[k] + beta * pa[k];   pb_[k] = ub[k] + beta * pb_[k];
      sa[k] = wa[k] + beta * sa[k];   sb[k] = wb[k] + beta * sb[k];
      xa[k] += alpha * pa[k];         xb[k] += alpha * pb_[k];
      ra_[k] -= alpha * sa[k];        rb_[k] -= alpha * sb[k];
    }
    gamma_old = gamma; alpha_old = alpha;
    cheb();
    dots();
  }

  float4* sol4 = reinterpret_cast<float4*>(sol);
  const int slot = 4 * row + c4;     // = i0/4
  sol4[sys * 256 + fa * 64 + slot] = make_float4(xa[0], xa[1], xa[2], xa[3]);
  sol4[sys * 256 + fb * 64 + slot] = make_float4(xb[0], xb[1], xb[2], xb[3]);
}

// ---------------------------------------------------------------------------
// Single fused kernel, point-to-point flag sync (no grid barrier):
//   blocks 0-7 : front (conv1 -> LDS -> conv2, SE on even) -> flag1[bid]
//   all blocks : wait flag1[2n],[2n+1] (n=bid>>3) -> pcg on wave 0 -> flag2
//   blocks 0-3 : wait flag2[8n..8n+7] -> GN + SE + post conv
// ---------------------------------------------------------------------------
__global__ __launch_bounds__(512, 1) void k_all(
    const float* __restrict__ x,
    const float* __restrict__ w1g, const float* __restrict__ b1g,
    const float* __restrict__ w1a, const float* __restrict__ b1a,
    const float* __restrict__ w2g, const float* __restrict__ b2g,
    const float* __restrict__ w2a, const float* __restrict__ b2a,
    const float* __restrict__ sw1, const float* __restrict__ sb1,
    const float* __restrict__ sw2, const float* __restrict__ sb2,
    const float* __restrict__ gn_w, const float* __restrict__ gn_b,
    const float* __restrict__ pw, const float* __restrict__ pb,
    float* __restrict__ grad, float* __restrict__ att,
    float* __restrict__ seb, float* __restrict__ solb,
    float* __restrict__ out, unsigned* __restrict__ bar) {
  __shared__ __attribute__((aligned(16))) unsigned char smem[84352];
  // front mapping
  unsigned short* Xl = (unsigned short*)smem;              // 32768 B
  unsigned short* Yl = (unsigned short*)(smem + 32768);    // 32768 B
  unsigned short* Wt = (unsigned short*)(smem + 65536);    // 18432 B
  float* sp  = (float*)(smem + 83968);                     // 256 B
  float* sh1 = (float*)(smem + 84224);                     // 128 B
  // post mapping (Hl disjoint from Wp; Wp staged after front is done)
  unsigned short* Hl = (unsigned short*)smem;              // 12288 B
  unsigned short* Wp = (unsigned short*)(smem + 12288);    // 55296 B
  float* rs  = (float*)(smem + 67584);                     // 32 B
  float* rs2 = (float*)(smem + 67616);                     // 32 B

  const int bid = blockIdx.x;
  const int t = threadIdx.x;
  unsigned* f1 = bar;               // 8 flags, stride 16 u32 (64 B)
  unsigned* f2 = bar + 32 * 16;     // 32 flags

  // ======================= phase 1: front =======================
  if (bid < 8) {
    const int br = bid & 1;
    const int n = bid >> 1;
    const float* inp = x + n * 64 * 256;

    {
      const int p = t & 255, hf = t >> 8;
      #pragma unroll
      for (int qq = 0; qq < 4; ++qq) {
        const int q8 = hf * 4 + qq;
        vs8 v;
        #pragma unroll
        for (int j = 0; j < 8; ++j) v[j] = (short)f2bf(inp[(8 * q8 + j) * 256 + p]);
        *(vs8*)&Xl[p * 64 + ((q8 ^ (p & 7)) << 3)] = v;
      }
    }

    if (br == 0) {
      if (t < 256) {
        const int c = t >> 2, part = t & 3;
        const float* xp = inp + c * 256 + part * 64;
        float s = 0.f;
        for (int k = 0; k < 64; ++k) s += xp[k];
        s += __shfl_xor(s, 1, 64);
        s += __shfl_xor(s, 2, 64);
        if (part == 0) sp[c] = s * (1.f / 256.f);
      }
      __syncthreads();
      if (t < 32) {
        float a = sb1[t];
        for (int k = 0; k < 64; ++k) a += sw1[t * 64 + k] * sp[k];
        sh1[t] = a > 0.f ? a : 0.01f * a;
      }
      __syncthreads();
      if (t < 16) {
        float a = sb2[t];
        for (int k = 0; k < 32; ++k) a += sw2[t * 32 + k] * sh1[k];
        seb[n * 16 + t] = 1.f / (1.f + __expf(-a));
      }
    }

    const float* w1 = br ? w1a : w1g;
    const float* b1 = br ? b1a : b1g;
    const int w = t >> 6, lane = t & 63;
    const int px = lane & 15, kg = lane >> 4;

    for (int ct = 0; ct < 4; ++ct) {
      __syncthreads();
      {
        const int col = t >> 5, sub = t & 31;
        const float* wp1 = w1 + ((ct * 16 + col) * 64 + sub * 2) * 9;
        #pragma unroll
        for (int cc = 0; cc < 2; ++cc) {
          const int ci = sub * 2 + cc;
          #pragma unroll
          for (int e = 0; e < 9; ++e)
            Wt[(e * 16 + col) * 64 + (ci ^ ((col & 7) << 3))] = f2bf(wp1[cc * 9 + e]);
        }
      }
      __syncthreads();
      vf4 acc[2];
      acc[0] = (vf4)0.f; acc[1] = (vf4)0.f;
      for (int e = 0; e < 9; ++e) {
        const int dy = e / 3 - 1, dx = e % 3 - 1;
        const bool xok = (dx == 0) || (dx < 0 ? (px > 0) : (px < 15));
        const int xoff = xok ? dx : 0;
        #pragma unroll
        for (int ks = 0; ks < 2; ++ks) {
          vs8 bf = *(const vs8*)&Wt[(e * 16 + px) * 64 + (((ks * 4 + kg) ^ (px & 7)) << 3)];
          #pragma unroll
          for (int mm = 0; mm < 2; ++mm) {
            const int yy = 2 * w + mm + dy;
            if (yy < 0 || yy > 15) continue;
            const int ps = yy * 16 + px + xoff;
            vs8 a = *(const vs8*)&Xl[ps * 64 + (((ks * 4 + kg) ^ (ps & 7)) << 3)];
            if (!xok) a = (vs8)(short)0;
            acc[mm] = __builtin_amdgcn_mfma_f32_16x16x32_bf16(a, bf, acc[mm], 0, 0, 0);
          }
        }
      }
      const int co = ct * 16 + px;
      const float bv = b1[co];
      #pragma unroll
      for (int mm = 0; mm < 2; ++mm) {
        const int y = 2 * w + mm;
        #pragma unroll
        for (int j = 0; j < 4; ++j) {
          float s = acc[mm][j] + bv;
          s = s > 0.f ? s : 0.01f * s;
          const int p = y * 16 + kg * 4 + j;
          Yl[p * 64 + (((co >> 3) ^ (p & 7)) << 3) + (co & 7)] = f2bf(s);
        }
      }
    }

    const float* w2 = br ? w2a : w2g;
    const float* b2 = br ? b2a : b2g;
    float* outp = (br ? att : grad) + n * 40 * 256;
    for (int ct = 0; ct < 3; ++ct) {
      __syncthreads();
      {
        const int col = t >> 5, sub = t & 31;
        const int co = ct * 16 + col;
        if (co < 40) {
          const float* wp2 = w2 + (co * 64 + sub * 2) * 9;
          #pragma unroll
          for (int cc = 0; cc < 2; ++cc) {
            const int ci = sub * 2 + cc;
            #pragma unroll
            for (int e = 0; e < 9; ++e)
              Wt[(e * 16 + col) * 64 + (ci ^ ((col & 7) << 3))] = f2bf(wp2[cc * 9 + e]);
          }
        } else {
          #pragma unroll
          for (int cc = 0; cc < 2; ++cc) {
            const int ci = sub * 2 + cc;
            #pragma unroll
            for (int e = 0; e < 9; ++e)
              Wt[(e * 16 + col) * 64 + (ci ^ ((col & 7) << 3))] = 0;
          }
        }
      }
      __syncthreads();
      vf4 acc[2];
      acc[0] = (vf4)0.f; acc[1] = (vf4)0.f;
      for (int e = 0; e < 9; ++e) {
        const int dy = e / 3 - 1, dx = e % 3 - 1;
        const bool xok = (dx == 0) || (dx < 0 ? (px > 0) : (px < 15));
        const int xoff = xok ? dx : 0;
        #pragma unroll
        for (int ks = 0; ks < 2; ++ks) {
          vs8 bf = *(const vs8*)&Wt[(e * 16 + px) * 64 + (((ks * 4 + kg) ^ (px & 7)) << 3)];
          #pragma unroll
          for (int mm = 0; mm < 2; ++mm) {
            const int yy = 2 * w + mm + dy;
            if (yy < 0 || yy > 15) continue;
            const int ps = yy * 16 + px + xoff;
            vs8 a = *(const vs8*)&Yl[ps * 64 + (((ks * 4 + kg) ^ (ps & 7)) << 3)];
            if (!xok) a = (vs8)(short)0;
            acc[mm] = __builtin_amdgcn_mfma_f32_16x16x32_bf16(a, bf, acc[mm], 0, 0, 0);
          }
        }
      }
      const int co = ct * 16 + px;
      if (co < 40) {
        const float bv = b2[co];
        #pragma unroll
        for (int mm = 0; mm < 2; ++mm) {
          const int y = 2 * w + mm;
          vf4 v = acc[mm];
          #pragma unroll
          for (int j = 0; j < 4; ++j) {
            float s = v[j] + bv;
            if (br) s = 1.f / (1.f + __expf(-s));
            v[j] = s;
          }
          *(vf4*)&outp[co * 256 + y * 16 + kg * 4] = v;
        }
      }
    }
  }
  __syncthreads();
  if (bid < 8 && t == 0) flag_set(f1 + bid * 16);

  // stage post-conv weights (pure input; LDS reuse is safe after the sync)
  if (bid < 4) {
    const int co = t >> 2, sub = t & 3;
    const float* wp0 = pw + (co * 16 + sub * 4) * 9;
    #pragma unroll
    for (int cc = 0; cc < 4; ++cc) {
      const int ci = sub * 4 + cc;
      #pragma unroll
      for (int e = 0; e < 9; ++e)
        Wp[(e * 128 + co) * 24 + ci] = f2bf(wp0[cc * 9 + e]);
    }
  }

  // ======================= phase 2: pcg =======================
  if (t == 0) {
    const int n8 = bid >> 3;
    flag_wait(f1 + (2 * n8) * 16);
    flag_wait(f1 + (2 * n8 + 1) * 16);
    __builtin_amdgcn_fence(__ATOMIC_ACQUIRE, "agent");
  }
  __syncthreads();
  if (t < 64) pcg_unit(bid, att, grad, solb, 100, 3e-6f);
  __syncthreads();
  if (t == 0) flag_set(f2 + bid * 16);

  // ======================= phase 3: post (blocks 0-3) ======================
  if (bid < 4) {
    const int n = bid;
    if (t == 0) {
      #pragma unroll
      for (int u = 0; u < 8; ++u) flag_wait(f2 + (8 * n + u) * 16);
      __builtin_amdgcn_fence(__ATOMIC_ACQUIRE, "agent");
    }
    __syncthreads();

    const int w = t >> 6, lane = t & 63;
    float v[8];
    {
      const vf4* s4 = (const vf4*)(solb + n * 4096 + 8 * t);
      vf4 a = s4[0], b = s4[1];
      v[0]=a[0];v[1]=a[1];v[2]=a[2];v[3]=a[3];v[4]=b[0];v[5]=b[1];v[6]=b[2];v[7]=b[3];
    }
    float s = 0.f, s2 = 0.f;
    #pragma unroll
    for (int k = 0; k < 8; ++k) { s += v[k]; s2 += v[k] * v[k]; }
    #pragma unroll
    for (int o = 1; o <= 32; o <<= 1) { s += __shfl_xor(s, o, 64); s2 += __shfl_xor(s2, o, 64); }
    if (lane == 0) { rs[w] = s; rs2[w] = s2; }
    __syncthreads();
    float sm = 0.f, sq = 0.f;
    #pragma unroll
    for (int k = 0; k < 8; ++k) { sm += rs[k]; sq += rs2[k]; }
    const float mu = sm * (1.f / 4096.f);
    const float rstd = rsqrtf(sq * (1.f / 4096.f) - mu * mu + 1e-5f);

    const int c = t >> 5;
    const int p0 = (8 * t) & 255;
    const float sev = seb[n * 16 + c];
    const float sc = rstd * gn_w[c] * sev;
    const float of = (gn_b[c] - mu * rstd * gn_w[c]) * sev;
    #pragma unroll
    for (int k = 0; k < 8; ++k) Hl[(p0 + k) * 24 + c] = f2bf(v[k] * sc + of);
    __syncthreads();

    const int cl = lane & 31, h = lane >> 5;
    const int px = cl & 15, y0 = 2 * w + (cl >> 4);
    vf16 acc[4];
    #pragma unroll
    for (int nt = 0; nt < 4; ++nt) acc[nt] = (vf16)0.f;
    for (int e = 0; e < 9; ++e) {
      const int dy = e / 3 - 1, dx = e % 3 - 1;
      const int yy = y0 + dy, xx = px + dx;
      const bool ok = (yy >= 0 && yy < 16 && xx >= 0 && xx < 16);
      const int ps = ok ? yy * 16 + xx : 0;
      vs8 a = *(const vs8*)&Hl[ps * 24 + h * 8];
      if (!ok) a = (vs8)(short)0;
      #pragma unroll
      for (int nt = 0; nt < 4; ++nt) {
        vs8 bf = *(const vs8*)&Wp[(e * 128 + nt * 32 + cl) * 24 + h * 8];
        acc[nt] = __builtin_amdgcn_mfma_f32_32x32x16_bf16(a, bf, acc[nt], 0, 0, 0);
      }
    }
    float* op = out + n * 32768;
    #pragma unroll
    for (int nt = 0; nt < 4; ++nt) {
      const int co = nt * 32 + cl;
      const float bv = pb[co];
      #pragma unroll
      for (int rq = 0; rq < 4; ++rq) {
        vf4 vv;
        #pragma unroll
        for (int j = 0; j < 4; ++j) vv[j] = acc[nt][rq * 4 + j] + bv;
        *(vf4*)&op[co * 256 + 32 * w + 8 * rq + 4 * h] = vv;
      }
    }
  }
}

extern "C" void kernel_launch(void* const* d_in, const int* in_sizes, int n_in,
                              void* d_out, int out_size, void* d_ws, size_t ws_size,
                              hipStream_t stream) {
  const float* x       = (const float*)d_in[0];
  const float* grad_w1 = (const float*)d_in[1];
  const float* grad_b1 = (const float*)d_in[2];
  const float* grad_w2 = (const float*)d_in[3];
  const float* grad_b2 = (const float*)d_in[4];
  const float* att_w1  = (const float*)d_in[5];
  const float* att_b1  = (const float*)d_in[6];
  const float* att_w2  = (const float*)d_in[7];
  const float* att_b2  = (const float*)d_in[8];
  const float* se_w1   = (const float*)d_in[9];
  const float* se_b1   = (const float*)d_in[10];
  const float* se_w2   = (const float*)d_in[11];
  const float* se_b2   = (const float*)d_in[12];
  const float* gn_w    = (const float*)d_in[13];
  const float* gn_b    = (const float*)d_in[14];
  const float* post_w  = (const float*)d_in[15];
  const float* post_b  = (const float*)d_in[16];
  float* out = (float*)d_out;
  float* ws = (float*)d_ws;

  float* gradb = ws;            // 40960 floats
  float* attb  = ws + 40960;    // 40960
  float* seb   = ws + 81920;    // 64
  float* solb  = ws + 81984;    // 16384
  unsigned* bar = (unsigned*)(ws + 98368); // 64 flag slots x 64 B = 4 KB

  hipMemsetAsync(bar, 0, 4096, stream);
  k_all<<<32, 512, 0, stream>>>(
      x, grad_w1, grad_b1, att_w1, att_b1,
      grad_w2, grad_b2, att_w2, att_b2,
      se_w1, se_b1, se_w2, se_b2,
      gn_w, gn_b, post_w, post_b,
      gradb, attb, seb, solb, out, bar);
}

// Round 13
// 61.917 us; speedup vs baseline: 1.6057x; 1.3393x over previous
//
#include <hip/hip_runtime.h>

#define NCHEB 8

typedef __attribute__((ext_vector_type(8))) short vs8;
typedef __attribute__((ext_vector_type(4))) float vf4;
typedef __attribute__((ext_vector_type(16))) float vf16;

__device__ __forceinline__ unsigned short f2bf(float f) {
  union { float f; unsigned int u; } x; x.f = f;
  unsigned int r = (x.u + 0x7FFFu + ((x.u >> 16) & 1u)) >> 16;
  return (unsigned short)r;
}

// DPP move: 0x138 = wave_shr:1 (lane l <- l-1), 0x130 = wave_shl:1 (l <- l+1),
// 0xB1 = quad_perm xor1, 0x4E = quad_perm xor2, 0x128 = row_ror:8 (xor8).
template<int CTRL>
__device__ __forceinline__ float dppf(float x) {
  return __int_as_float(__builtin_amdgcn_mov_dpp(__float_as_int(x), CTRL, 0xF, 0xF, true));
}

// ---------------------------------------------------------------------------
// MFMA 3x3 SAME conv, co-tile split (R8's proven kernel, unchanged).
// ---------------------------------------------------------------------------
template<int COUT, int TILES, bool SE>
__global__ __launch_bounds__(256) void k_conv(
    const float* __restrict__ inA, const float* __restrict__ inB,
    const float* __restrict__ wA, const float* __restrict__ bA,
    const float* __restrict__ wB, const float* __restrict__ bB,
    float* __restrict__ outA, float* __restrict__ outB,
    int actA, int actB,
    const float* __restrict__ x,
    const float* __restrict__ sw1, const float* __restrict__ sb1,
    const float* __restrict__ sw2, const float* __restrict__ sb2,
    float* __restrict__ seo) {
  __shared__ unsigned short Xl[256 * 64];
  __shared__ unsigned short Wl[9 * 16 * 64];
  __shared__ float sp[64];
  __shared__ float sh1[32];
  const int b = blockIdx.x;
  const int t = threadIdx.x;

  if (SE && b >= 8 * TILES) {
    const int n = b - 8 * TILES;
    const int c = t >> 2, part = t & 3;
    const float* xp = x + (n * 64 + c) * 256 + part * 64;
    float s = 0.f;
    for (int k = 0; k < 64; ++k) s += xp[k];
    s += __shfl_xor(s, 1, 64);
    s += __shfl_xor(s, 2, 64);
    if (part == 0) sp[c] = s * (1.f / 256.f);
    __syncthreads();
    if (t < 32) {
      float a = sb1[t];
      for (int k = 0; k < 64; ++k) a += sw1[t * 64 + k] * sp[k];
      sh1[t] = a > 0.f ? a : 0.01f * a;
    }
    __syncthreads();
    if (t < 16) {
      float a = sb2[t];
      for (int k = 0; k < 32; ++k) a += sw2[t * 32 + k] * sh1[k];
      seo[n * 16 + t] = 1.f / (1.f + __expf(-a));
    }
    return;
  }

  const int n = b & 3;
  const int q = b >> 2;
  const int br = (q >= TILES) ? 1 : 0;
  const int ct = q - br * TILES;
  const int co0 = ct * 16;
  const float* inp = (br ? inB : inA) + n * 64 * 256;
  const float* wsrc = br ? wB : wA;
  const float* bias = br ? bB : bA;
  float* outp = (br ? outB : outA) + n * COUT * 256;
  const int act = br ? actB : actA;

  {
    const int p = t;
    #pragma unroll
    for (int q8 = 0; q8 < 8; ++q8) {
      vs8 v;
      #pragma unroll
      for (int j = 0; j < 8; ++j) v[j] = (short)f2bf(inp[(8 * q8 + j) * 256 + p]);
      *(vs8*)&Xl[p * 64 + ((q8 ^ (p & 7)) << 3)] = v;
    }
  }
  {
    const int col = t >> 4;
    const int sub = t & 15;
    const int co = co0 + col;
    if (co < COUT) {
      const float* wp = wsrc + (co * 64 + sub * 4) * 9;
      #pragma unroll
      for (int cc = 0; cc < 4; ++cc) {
        const int ci = sub * 4 + cc;
        #pragma unroll
        for (int e = 0; e < 9; ++e)
          Wl[(e * 16 + col) * 64 + (ci ^ ((col & 7) << 3))] = f2bf(wp[cc * 9 + e]);
      }
    } else {
      #pragma unroll
      for (int cc = 0; cc < 4; ++cc) {
        const int ci = sub * 4 + cc;
        #pragma unroll
        for (int e = 0; e < 9; ++e)
          Wl[(e * 16 + col) * 64 + (ci ^ ((col & 7) << 3))] = 0;
      }
    }
  }
  __syncthreads();

  const int w = t >> 6, lane = t & 63;
  const int px = lane & 15, kg = lane >> 4;
  vf4 acc[4];
  #pragma unroll
  for (int mt = 0; mt < 4; ++mt) acc[mt] = (vf4)0.f;

  for (int e = 0; e < 9; ++e) {
    const int dy = e / 3 - 1, dx = e % 3 - 1;
    const bool xok = (dx == 0) || (dx < 0 ? (px > 0) : (px < 15));
    const int xoff = xok ? dx : 0;
    #pragma unroll
    for (int ks = 0; ks < 2; ++ks) {
      vs8 bf = *(const vs8*)&Wl[(e * 16 + px) * 64 + (((ks * 4 + kg) ^ (px & 7)) << 3)];
      #pragma unroll
      for (int mt = 0; mt < 4; ++mt) {
        const int yy = 4 * w + mt + dy;
        if (yy < 0 || yy > 15) continue;
        const int ps = yy * 16 + px + xoff;
        vs8 a = *(const vs8*)&Xl[ps * 64 + (((ks * 4 + kg) ^ (ps & 7)) << 3)];
        if (!xok) a = (vs8)(short)0;
        acc[mt] = __builtin_amdgcn_mfma_f32_16x16x32_bf16(a, bf, acc[mt], 0, 0, 0);
      }
    }
  }

  const int co = co0 + px;
  if (co < COUT) {
    const float bv = bias[co];
    #pragma unroll
    for (int mt = 0; mt < 4; ++mt) {
      const int y = 4 * w + mt;
      vf4 v = acc[mt];
      #pragma unroll
      for (int j = 0; j < 4; ++j) {
        float s = v[j] + bv;
        if (act == 1) s = s > 0.f ? s : 0.01f * s;
        else if (act == 2) s = 1.f / (1.f + __expf(-s));
        v[j] = s;
      }
      *(vf4*)&outp[co * 256 + y * 16 + kg * 4] = v;
    }
  }
}

// ---------------------------------------------------------------------------
// Fused GroupNorm(1,16) + SE + post conv (R8's proven kernel, unchanged).
// ---------------------------------------------------------------------------
__global__ __launch_bounds__(512) void k_post(
    const float* __restrict__ sol, const float* __restrict__ se,
    const float* __restrict__ gn_w, const float* __restrict__ gn_b,
    const float* __restrict__ pw, const float* __restrict__ pb,
    float* __restrict__ out) {
  __shared__ unsigned short Hl[256 * 24];
  __shared__ unsigned short Wp[9 * 128 * 24];
  __shared__ float rs[8];
  __shared__ float rs2[8];
  const int n = blockIdx.x;
  const int t = threadIdx.x;
  const int w = t >> 6, lane = t & 63;

  float v[8];
  {
    const vf4* s4 = (const vf4*)(sol + n * 4096 + 8 * t);
    vf4 a = s4[0], b = s4[1];
    v[0]=a[0];v[1]=a[1];v[2]=a[2];v[3]=a[3];v[4]=b[0];v[5]=b[1];v[6]=b[2];v[7]=b[3];
  }
  float s = 0.f, s2 = 0.f;
  #pragma unroll
  for (int k = 0; k < 8; ++k) { s += v[k]; s2 += v[k] * v[k]; }
  #pragma unroll
  for (int o = 1; o <= 32; o <<= 1) { s += __shfl_xor(s, o, 64); s2 += __shfl_xor(s2, o, 64); }
  if (lane == 0) { rs[w] = s; rs2[w] = s2; }

  {
    const int co = t >> 2, sub = t & 3;
    const float* wp0 = pw + (co * 16 + sub * 4) * 9;
    #pragma unroll
    for (int cc = 0; cc < 4; ++cc) {
      const int ci = sub * 4 + cc;
      #pragma unroll
      for (int e = 0; e < 9; ++e)
        Wp[(e * 128 + co) * 24 + ci] = f2bf(wp0[cc * 9 + e]);
    }
  }
  __syncthreads();
  float sm = 0.f, sq = 0.f;
  #pragma unroll
  for (int k = 0; k < 8; ++k) { sm += rs[k]; sq += rs2[k]; }
  const float mu = sm * (1.f / 4096.f);
  const float rstd = rsqrtf(sq * (1.f / 4096.f) - mu * mu + 1e-5f);

  const int c = t >> 5;
  const int p0 = (8 * t) & 255;
  const float sev = se[n * 16 + c];
  const float sc = rstd * gn_w[c] * sev;
  const float of = (gn_b[c] - mu * rstd * gn_w[c]) * sev;
  #pragma unroll
  for (int k = 0; k < 8; ++k) Hl[(p0 + k) * 24 + c] = f2bf(v[k] * sc + of);
  __syncthreads();

  const int cl = lane & 31, h = lane >> 5;
  const int px = cl & 15, y0 = 2 * w + (cl >> 4);
  vf16 acc[4];
  #pragma unroll
  for (int nt = 0; nt < 4; ++nt) acc[nt] = (vf16)0.f;
  for (int e = 0; e < 9; ++e) {
    const int dy = e / 3 - 1, dx = e % 3 - 1;
    const int yy = y0 + dy, xx = px + dx;
    const bool ok = (yy >= 0 && yy < 16 && xx >= 0 && xx < 16);
    const int ps = ok ? yy * 16 + xx : 0;
    vs8 a = *(const vs8*)&Hl[ps * 24 + h * 8];
    if (!ok) a = (vs8)(short)0;
    #pragma unroll
    for (int nt = 0; nt < 4; ++nt) {
      vs8 bf = *(const vs8*)&Wp[(e * 128 + nt * 32 + cl) * 24 + h * 8];
      acc[nt] = __builtin_amdgcn_mfma_f32_32x32x16_bf16(a, bf, acc[nt], 0, 0, 0);
    }
  }
  float* op = out + n * 32768;
  #pragma unroll
  for (int nt = 0; nt < 4; ++nt) {
    const int co = nt * 32 + cl;
    const float bv = pb[co];
    #pragma unroll
    for (int rq = 0; rq < 4; ++rq) {
      vf4 vv;
      #pragma unroll
      for (int j = 0; j < 4; ++j) vv[j] = acc[nt][rq * 4 + j] + bv;
      *(vf4*)&op[co * 256 + 32 * w + 8 * rq + 4 * h] = vv;
    }
  }
}

// ---------------------------------------------------------------------------
// Wave-local Chebyshev(NCHEB)-PCG, DPP SpMV (R12's verified version) as a
// standalone dispatch: 32 blocks x 64 threads, 1 wave/CU, no contention.
// Lane l owns pixels (y=l&15, x=4*(l>>4)+k); up/down = DPP wave shifts.
// ---------------------------------------------------------------------------
__global__ __launch_bounds__(64) void k_pcg(
    const float* __restrict__ att, const float* __restrict__ grad,
    float* __restrict__ sol, int maxit, float tol2) {
  const int unit = blockIdx.x;
  const int sys = unit >> 1;
  const int wv = unit & 1;
  const int l = threadIdx.x & 63;
  const int row = l & 15;
  const int c4 = l >> 4;
  const int i0 = 16 * row + 4 * c4;

  const int n = sys >> 2, g = sys & 3;
  const float* ab = att + (n * 40 + g * 10) * 256;
  const float* gb = grad + (n * 40 + g * 10) * 256;

  int era, eda, erb, edb, ec, fa, fb;
  if (wv == 0) { fa = 0; fb = 2; era = 4; eda = 9; erb = 2; edb = 7; ec = 0; }
  else         { fa = 1; fb = 3; era = 8; eda = 5; erb = 6; edb = 3; ec = 1; }

  auto L4 = [](const float* p) { return *reinterpret_cast<const float4*>(p); };
  auto unp = [](float4 v, float* o) { o[0] = v.x; o[1] = v.y; o[2] = v.z; o[3] = v.w; };

  float wLa[4], wRa[4], wUa[4], wDa[4], wXa[4], dga[4], iva[4], rsa[4];
  float wLb[4], wRb[4], wUb[4], wDb[4], wXb[4], dgb[4], ivb[4], rsb[4];

  float rA[4], gA[4], dA[4], hA[4], uA[4] = {0,0,0,0}, vA[4] = {0,0,0,0};
  unp(L4(ab + era * 256 + i0), rA); unp(L4(gb + era * 256 + i0), gA);
  unp(L4(ab + eda * 256 + i0), dA); unp(L4(gb + eda * 256 + i0), hA);
  if (row > 0) { unp(L4(ab + eda * 256 + i0 - 16), uA); unp(L4(gb + eda * 256 + i0 - 16), vA); }
  float rlA = (l > 0) ? ab[era * 256 + i0 - 1] : 0.f;
  float glA = (l > 0) ? gb[era * 256 + i0 - 1] : 0.f;
  float cX[4], gX[4], cU[4] = {0,0,0,0}, gU[4] = {0,0,0,0};
  unp(L4(ab + ec * 256 + i0), cX); unp(L4(gb + ec * 256 + i0), gX);
  float clX = 0.f, glX = 0.f;
  if (wv == 0) { if (l > 0) { clX = ab[ec * 256 + i0 - 1]; glX = gb[ec * 256 + i0 - 1]; } }
  else if (row > 0) { unp(L4(ab + ec * 256 + i0 - 16), cU); unp(L4(gb + ec * 256 + i0 - 16), gU); }

  #pragma unroll
  for (int k = 0; k < 4; ++k) {
    wRa[k] = (k < 3 || c4 < 3) ? rA[k] * rA[k] : 0.f;
    wLa[k] = (k > 0) ? rA[k-1] * rA[k-1] : ((c4 > 0) ? rlA * rlA : 0.f);
    wDa[k] = (row < 15) ? dA[k] * dA[k] : 0.f;
    wUa[k] = (row > 0) ? uA[k] * uA[k] : 0.f;
    float rhs = wRa[k] * gA[k] - wLa[k] * ((k > 0) ? gA[k-1] : glA)
              + wDa[k] * hA[k] - wUa[k] * vA[k];
    float wx, gx;
    if (wv == 0) {
      wx = (k > 0) ? cX[k-1] * cX[k-1] : ((c4 > 0) ? clX * clX : 0.f);
      gx = (k > 0) ? gX[k-1] : glX;
    } else {
      wx = (row > 0) ? cU[k] * cU[k] : 0.f;
      gx = gU[k];
    }
    wXa[k] = wx;
    rhs -= wx * gx;
    rsa[k] = rhs;
    dga[k] = 1e-12f + wRa[k] + wLa[k] + wDa[k] + wUa[k] + wx;
  }

  float rB[4], gB[4], dB[4], hB[4], uB[4] = {0,0,0,0}, vB[4] = {0,0,0,0};
  unp(L4(ab + erb * 256 + i0), rB); unp(L4(gb + erb * 256 + i0), gB);
  unp(L4(ab + edb * 256 + i0), dB); unp(L4(gb + edb * 256 + i0), hB);
  if (row > 0) { unp(L4(ab + edb * 256 + i0 - 16), uB); unp(L4(gb + edb * 256 + i0 - 16), vB); }
  float rlB = (l > 0) ? ab[erb * 256 + i0 - 1] : 0.f;
  float glB = (l > 0) ? gb[erb * 256 + i0 - 1] : 0.f;

  #pragma unroll
  for (int k = 0; k < 4; ++k) {
    wRb[k] = (k < 3 || c4 < 3) ? rB[k] * rB[k] : 0.f;
    wLb[k] = (k > 0) ? rB[k-1] * rB[k-1] : ((c4 > 0) ? rlB * rlB : 0.f);
    wDb[k] = (row < 15) ? dB[k] * dB[k] : 0.f;
    wUb[k] = (row > 0) ? uB[k] * uB[k] : 0.f;
    float wx;
    if (wv == 0) wx = (k < 3 || c4 < 3) ? cX[k] * cX[k] : 0.f;
    else         wx = (row < 15) ? cX[k] * cX[k] : 0.f;
    wXb[k] = wx;
    rsb[k] = wRb[k] * gB[k] - wLb[k] * ((k > 0) ? gB[k-1] : glB)
           + wDb[k] * hB[k] - wUb[k] * vB[k]
           + wx * gX[k];
    dgb[k] = 1e-12f + wRb[k] + wLb[k] + wDb[k] + wUb[k] + wx;
  }

  if (l == 63) {
    float wr = rA[3] * rA[3], wd = dA[3] * dA[3];
    dga[3] += wr + wd;
    rsa[3] += wr * gA[3] + wd * hA[3];
    float wc = cX[3] * cX[3], wrb = rB[3] * rB[3], wdb = dB[3] * dB[3];
    dgb[3] += wc + wrb + wdb;
    rsb[3] += wc * gX[3] + wrb * gB[3] + wdb * hB[3];
  }
  #pragma unroll
  for (int k = 0; k < 4; ++k) { iva[k] = 1.f / dga[k]; ivb[k] = 1.f / dgb[k]; }

  float ua[4], ub[4], wa[4], wb[4];

  auto spmv = [&](const float (&ia_)[4], const float (&ib_)[4],
                  float (&oa)[4], float (&ob)[4]) {
    float aL = __shfl_up(ia_[3], 16, 64);
    float aR = __shfl_down(ia_[0], 16, 64);
    float bL = __shfl_up(ib_[3], 16, 64);
    float bR = __shfl_down(ib_[0], 16, 64);
    float aU[4], aD[4], bU[4], bD[4];
    #pragma unroll
    for (int k = 0; k < 4; ++k) {
      aU[k] = dppf<0x138>(ia_[k]);
      aD[k] = dppf<0x130>(ia_[k]);
      bU[k] = dppf<0x138>(ib_[k]);
      bD[k] = dppf<0x130>(ib_[k]);
    }
    float uaL[4] = {aL, ia_[0], ia_[1], ia_[2]};
    float uaR[4] = {ia_[1], ia_[2], ia_[3], aR};
    float ubL[4] = {bL, ib_[0], ib_[1], ib_[2]};
    float ubR[4] = {ib_[1], ib_[2], ib_[3], bR};
    #pragma unroll
    for (int k = 0; k < 4; ++k) {
      float cA = (wv == 0) ? ubL[k] : bU[k];
      float cB = (wv == 0) ? uaR[k] : aD[k];
      oa[k] = dga[k] * ia_[k] - wLa[k] * uaL[k] - wRa[k] * uaR[k]
            - wUa[k] * aU[k] - wDa[k] * aD[k] - wXa[k] * cA;
      ob[k] = dgb[k] * ib_[k] - wLb[k] * ubL[k] - wRb[k] * ubR[k]
            - wUb[k] * bU[k] - wDb[k] * bD[k] - wXb[k] * cB;
    }
  };

  constexpr float lo = 0.01f, hi = 2.0f;
  constexpr float th = (hi + lo) * 0.5f, dl = (hi - lo) * 0.5f, s1 = th / dl;

  float xa[4] = {0,0,0,0}, xb[4] = {0,0,0,0};
  float ra_[4], rb_[4], pa[4] = {0,0,0,0}, pb_[4] = {0,0,0,0};
  float sa[4] = {0,0,0,0}, sb[4] = {0,0,0,0};
  #pragma unroll
  for (int k = 0; k < 4; ++k) { ra_[k] = rsa[k]; rb_[k] = rsb[k]; }

  auto cheb = [&]() {
    float da_[4], db_[4], ta[4], tb[4], qa[4], qb[4];
    #pragma unroll
    for (int k = 0; k < 4; ++k) {
      da_[k] = (1.0f / th) * iva[k] * ra_[k];
      db_[k] = (1.0f / th) * ivb[k] * rb_[k];
      ua[k] = da_[k]; ub[k] = db_[k];
    }
    spmv(da_, db_, ta, tb);
    #pragma unroll
    for (int k = 0; k < 4; ++k) {
      wa[k] = ta[k]; wb[k] = tb[k];
      qa[k] = ra_[k] - ta[k]; qb[k] = rb_[k] - tb[k];
    }
    float rho = 1.0f / s1;
    #pragma unroll
    for (int j = 1; j < NCHEB; ++j) {
      float rho2 = 1.0f / (2.0f * s1 - rho);
      float c1 = rho2 * rho, c2 = 2.0f * rho2 / dl;
      #pragma unroll
      for (int k = 0; k < 4; ++k) {
        da_[k] = c1 * da_[k] + c2 * iva[k] * qa[k];
        db_[k] = c1 * db_[k] + c2 * ivb[k] * qb[k];
        ua[k] += da_[k]; ub[k] += db_[k];
      }
      spmv(da_, db_, ta, tb);
      #pragma unroll
      for (int k = 0; k < 4; ++k) {
        wa[k] += ta[k]; wb[k] += tb[k];
        qa[k] -= ta[k]; qb[k] -= tb[k];
      }
      rho = rho2;
    }
  };

  float gamma, delta;
  auto dots = [&]() {
    float gp = 0.f, dp = 0.f;
    #pragma unroll
    for (int k = 0; k < 4; ++k) {
      gp += ra_[k] * ua[k] + rb_[k] * ub[k];
      dp += wa[k] * ua[k] + wb[k] * ub[k];
    }
    gp += dppf<0xB1>(gp);            dp += dppf<0xB1>(dp);
    gp += dppf<0x4E>(gp);            dp += dppf<0x4E>(dp);
    gp += __shfl_xor(gp, 4, 64);     dp += __shfl_xor(dp, 4, 64);
    gp += dppf<0x128>(gp);           dp += dppf<0x128>(dp);
    gp += __shfl_xor(gp, 16, 64);    dp += __shfl_xor(dp, 16, 64);
    gp += __shfl_xor(gp, 32, 64);    dp += __shfl_xor(dp, 32, 64);
    gamma = gp; delta = dp;
  };

  cheb();
  dots();
  const float thresh = tol2 * gamma;
  float gamma_old = gamma, alpha_old = 1.f;

  for (int it = 0; it < maxit && gamma > thresh; ++it) {
    float beta = (it == 0) ? 0.f : gamma / gamma_old;
    float alpha = (it == 0) ? gamma / delta
                            : gamma / (delta - beta * gamma / alpha_old);
    #pragma unroll
    for (int k = 0; k < 4; ++k) {
      pa[k] = ua[k] + beta * pa[k];   pb_[k] = ub[k] + beta * pb_[k];
      sa[k] = wa[k] + beta * sa[k];   sb[k] = wb[k] + beta * sb[k];
      xa[k] += alpha * pa[k];         xb[k] += alpha * pb_[k];
      ra_[k] -= alpha * sa[k];        rb_[k] -= alpha * sb[k];
    }
    gamma_old = gamma; alpha_old = alpha;
    cheb();
    dots();
  }

  float4* sol4 = reinterpret_cast<float4*>(sol);
  const int slot = 4 * row + c4;
  sol4[sys * 256 + fa * 64 + slot] = make_float4(xa[0], xa[1], xa[2], xa[3]);
  sol4[sys * 256 + fb * 64 + slot] = make_float4(xb[0], xb[1], xb[2], xb[3]);
}

extern "C" void kernel_launch(void* const* d_in, const int* in_sizes, int n_in,
                              void* d_out, int out_size, void* d_ws, size_t ws_size,
                              hipStream_t stream) {
  const float* x       = (const float*)d_in[0];
  const float* grad_w1 = (const float*)d_in[1];
  const float* grad_b1 = (const float*)d_in[2];
  const float* grad_w2 = (const float*)d_in[3];
  const float* grad_b2 = (const float*)d_in[4];
  const float* att_w1  = (const float*)d_in[5];
  const float* att_b1  = (const float*)d_in[6];
  const float* att_w2  = (const float*)d_in[7];
  const float* att_b2  = (const float*)d_in[8];
  const float* se_w1   = (const float*)d_in[9];
  const float* se_b1   = (const float*)d_in[10];
  const float* se_w2   = (const float*)d_in[11];
  const float* se_b2   = (const float*)d_in[12];
  const float* gn_w    = (const float*)d_in[13];
  const float* gn_b    = (const float*)d_in[14];
  const float* post_w  = (const float*)d_in[15];
  const float* post_b  = (const float*)d_in[16];
  float* out = (float*)d_out;
  float* ws = (float*)d_ws;

  float* t1    = ws;                // 65536 (grad conv1 out)
  float* t2    = ws + 65536;        // 65536 (att conv1 out)
  float* gradb = ws + 131072;       // 40960
  float* attb  = ws + 172032;       // 40960
  float* seb   = ws + 212992;       // 64
  float* solb  = ws;                // 16384 (reuses t1 after conv2)

  // conv1: 2 branches x 4 images x 4 co-tiles = 32 blocks + 4 SE blocks
  k_conv<64, 4, true><<<36, 256, 0, stream>>>(
      x, x, grad_w1, grad_b1, att_w1, att_b1, t1, t2, 1, 1,
      x, se_w1, se_b1, se_w2, se_b2, seb);
  // conv2: 2 x 4 x 3 co-tiles = 24 blocks
  k_conv<40, 3, false><<<24, 256, 0, stream>>>(
      t1, t2, grad_w2, grad_b2, att_w2, att_b2, gradb, attb, 0, 2,
      nullptr, nullptr, nullptr, nullptr, nullptr, nullptr);
  // pcg: 32 blocks x 1 wave (uncontended), DPP SpMV
  k_pcg<<<32, 64, 0, stream>>>(attb, gradb, solb, 100, 3e-6f);
  k_post<<<4, 512, 0, stream>>>(solb, seb, gn_w, gn_b, post_w, post_b, out);
}